// Round 2
// baseline (158.864 us; speedup 1.0000x reference)
//
#include <hip/hip_runtime.h>

// HeadDetectorLoss: scalar loss over N rows (N=4194304).
//   prediction (N,6) f32: [:,0:2]=class logits, [:,2:6]=box pred
//   target_class (N,) i32 in {0,1}; target_box (N,4) f32
//   out = mean(nll) + 10 * sum(mse*mask) / (1e-6 + sum(mask))
// Memory-bound streaming reduction: 184.5 MB read, 4 B written.
// Single fused kernel: grid-stride quad processing (4 rows/quad, 2 quads/thread
// loaded up-front for MLP), block partials in d_ws, last-block-done finalize.

#define BLOCK 256
#define MAXGRID 2048

struct Quad { float4 p[6]; float4 t[4]; int4 c; };

__device__ __forceinline__ void load_quad(const float* __restrict__ pred,
                                          const float* __restrict__ tbox,
                                          const int*   __restrict__ tcls,
                                          int q, Quad& Q) {
  #pragma unroll
  for (int i = 0; i < 6; ++i)
    Q.p[i] = *reinterpret_cast<const float4*>(pred + 24 * (long long)q + 4 * i);
  #pragma unroll
  for (int i = 0; i < 4; ++i)
    Q.t[i] = *reinterpret_cast<const float4*>(tbox + 16 * (long long)q + 4 * i);
  Q.c = *reinterpret_cast<const int4*>(tcls + 4 * (long long)q);
}

__device__ __forceinline__ void acc_quad(const Quad& Q, float& nll, float& box, float& cnt) {
  const float* pr = reinterpret_cast<const float*>(Q.p);
  const float* tb = reinterpret_cast<const float*>(Q.t);
  const int*   tc = reinterpret_cast<const int*>(&Q.c);
  #pragma unroll
  for (int r = 0; r < 4; ++r) {
    float l0 = pr[6*r], l1 = pr[6*r+1];
    float m   = fmaxf(l0, l1);
    float lse = m + __logf(__expf(l0 - m) + __expf(l1 - m));
    nll += lse - (tc[r] == 0 ? l0 : l1);
    float d0 = pr[6*r+2] - tb[4*r+0], d1 = pr[6*r+3] - tb[4*r+1];
    float d2 = pr[6*r+4] - tb[4*r+2], d3 = pr[6*r+5] - tb[4*r+3];
    float mse = 0.25f * (d0*d0 + d1*d1 + d2*d2 + d3*d3);
    if (tc[r] != 0) { box += mse; cnt += 1.f; }
  }
}

__global__ __launch_bounds__(BLOCK) void hdl_fused(
    const float* __restrict__ pred,
    const int*   __restrict__ tcls,
    const float* __restrict__ tbox,
    float* __restrict__ part,          // [3*grid] interleaved partials
    unsigned int* __restrict__ counter, // zeroed by memset node each call
    float* __restrict__ out,
    int nrows)
{
  const int tid    = blockIdx.x * BLOCK + threadIdx.x;
  const int stride = gridDim.x * BLOCK;
  const int nquads = nrows >> 2;

  float nll = 0.f, box = 0.f, cnt = 0.f;

  // Two quads per thread, loads issued up-front for MLP.
  {
    const int q0 = tid, q1 = tid + stride;
    Quad A, B;
    const bool h0 = q0 < nquads, h1 = q1 < nquads;
    if (h0) load_quad(pred, tbox, tcls, q0, A);
    if (h1) load_quad(pred, tbox, tcls, q1, B);
    if (h0) acc_quad(A, nll, box, cnt);
    if (h1) acc_quad(B, nll, box, cnt);
  }
  // Generic continuation (not taken at N=4194304 with grid=2048).
  for (int q = tid + 2 * stride; q < nquads; q += stride) {
    Quad A; load_quad(pred, tbox, tcls, q, A); acc_quad(A, nll, box, cnt);
  }
  // Tail rows (nrows % 4), handled scalar by one thread.
  if (tid == 0) {
    for (int r = nquads << 2; r < nrows; ++r) {
      float l0 = pred[6ll*r], l1 = pred[6ll*r+1];
      float m = fmaxf(l0, l1);
      float lse = m + __logf(__expf(l0 - m) + __expf(l1 - m));
      int c = tcls[r];
      nll += lse - (c == 0 ? l0 : l1);
      float d0 = pred[6ll*r+2] - tbox[4ll*r+0], d1 = pred[6ll*r+3] - tbox[4ll*r+1];
      float d2 = pred[6ll*r+4] - tbox[4ll*r+2], d3 = pred[6ll*r+5] - tbox[4ll*r+3];
      float mse = 0.25f * (d0*d0 + d1*d1 + d2*d2 + d3*d3);
      if (c != 0) { box += mse; cnt += 1.f; }
    }
  }

  // Wave64 tree reduction.
  #pragma unroll
  for (int off = 32; off > 0; off >>= 1) {
    nll += __shfl_down(nll, off);
    box += __shfl_down(box, off);
    cnt += __shfl_down(cnt, off);
  }

  __shared__ float s[3][BLOCK / 64];
  __shared__ bool  lastBlock;
  const int lane = threadIdx.x & 63, w = threadIdx.x >> 6;
  if (lane == 0) { s[0][w] = nll; s[1][w] = box; s[2][w] = cnt; }
  __syncthreads();
  if (threadIdx.x == 0) {
    float a = 0.f, b = 0.f, cn = 0.f;
    #pragma unroll
    for (int i = 0; i < BLOCK / 64; ++i) { a += s[0][i]; b += s[1][i]; cn += s[2][i]; }
    __hip_atomic_store(&part[3*blockIdx.x+0], a,  __ATOMIC_RELAXED, __HIP_MEMORY_SCOPE_AGENT);
    __hip_atomic_store(&part[3*blockIdx.x+1], b,  __ATOMIC_RELAXED, __HIP_MEMORY_SCOPE_AGENT);
    __hip_atomic_store(&part[3*blockIdx.x+2], cn, __ATOMIC_RELAXED, __HIP_MEMORY_SCOPE_AGENT);
    __threadfence();
    unsigned prev = __hip_atomic_fetch_add(counter, 1u, __ATOMIC_ACQ_REL, __HIP_MEMORY_SCOPE_AGENT);
    lastBlock = (prev == gridDim.x - 1);
  }
  __syncthreads();

  if (lastBlock) {
    __threadfence();
    float A = 0.f, B = 0.f, C = 0.f;
    for (int i = threadIdx.x; i < (int)gridDim.x; i += BLOCK) {
      A += __hip_atomic_load(&part[3*i+0], __ATOMIC_RELAXED, __HIP_MEMORY_SCOPE_AGENT);
      B += __hip_atomic_load(&part[3*i+1], __ATOMIC_RELAXED, __HIP_MEMORY_SCOPE_AGENT);
      C += __hip_atomic_load(&part[3*i+2], __ATOMIC_RELAXED, __HIP_MEMORY_SCOPE_AGENT);
    }
    #pragma unroll
    for (int off = 32; off > 0; off >>= 1) {
      A += __shfl_down(A, off);
      B += __shfl_down(B, off);
      C += __shfl_down(C, off);
    }
    __syncthreads();  // s[] reuse
    if (lane == 0) { s[0][w] = A; s[1][w] = B; s[2][w] = C; }
    __syncthreads();
    if (threadIdx.x == 0) {
      float sa = 0.f, sb = 0.f, sc = 0.f;
      #pragma unroll
      for (int i = 0; i < BLOCK / 64; ++i) { sa += s[0][i]; sb += s[1][i]; sc += s[2][i]; }
      out[0] = sa / (float)nrows + 10.0f * sb / (1e-6f + sc);
    }
  }
}

extern "C" void kernel_launch(void* const* d_in, const int* in_sizes, int n_in,
                              void* d_out, int out_size, void* d_ws, size_t ws_size,
                              hipStream_t stream) {
  const float* pred = (const float*)d_in[0];
  const int*   tcls = (const int*)d_in[1];
  const float* tbox = (const float*)d_in[2];
  float* out  = (float*)d_out;
  float* part = (float*)d_ws;                               // 3*MAXGRID floats = 24 KB
  unsigned int* counter = (unsigned int*)((char*)d_ws + 3 * MAXGRID * sizeof(float));
  const int nrows  = in_sizes[1];                           // N from target_class
  const int nquads = nrows >> 2;

  int grid = (nquads + 2 * BLOCK - 1) / (2 * BLOCK);        // 2 quads per thread
  if (grid > MAXGRID) grid = MAXGRID;
  if (grid < 1) grid = 1;

  hipMemsetAsync(counter, 0, sizeof(unsigned int), stream); // reset finalize counter
  hdl_fused<<<grid, BLOCK, 0, stream>>>(pred, tcls, tbox, part, counter, out, nrows);
}